// Round 8
// baseline (186.153 us; speedup 1.0000x reference)
//
#include <hip/hip_runtime.h>
#include <hip/hip_bf16.h>

#define CC 16
#define LL 8192
#define SS 8191   // L-1
#define EE 512
#define HH 256
#define MM 128
#define TOPK 30

typedef __attribute__((ext_vector_type(8))) short short8;
typedef __attribute__((ext_vector_type(4))) float f32x4;
typedef __attribute__((ext_vector_type(4))) unsigned int u32x4;

static __device__ __forceinline__ unsigned short f2bf(float f) {
    unsigned u = __builtin_bit_cast(unsigned, f);
    u += 0x7FFFu + ((u >> 16) & 1u);   // RNE
    return (unsigned short)(u >> 16);
}

static __device__ __forceinline__ unsigned pk2(float lo, float hi) {
    __hip_bfloat162 t = __float22bfloat162_rn(float2{lo, hi});
    unsigned u;
    __builtin_memcpy(&u, &t, 4);
    return u;
}

// 8 f32 -> 8 bf16 (v_cvt_pk_bf16_f32)
static __device__ __forceinline__ short8 cvt8(const float4 a, const float4 b) {
    u32x4 uv;
    uv[0] = pk2(a.x, a.y);
    uv[1] = pk2(a.z, a.w);
    uv[2] = pk2(b.x, b.y);
    uv[3] = pk2(b.z, b.w);
    return __builtin_bit_cast(short8, uv);
}

// async global->LDS, 16B per lane (global_load_lds_dwordx4)
static __device__ __forceinline__ void gl2lds16(const float* g, unsigned char* l) {
    __builtin_amdgcn_global_load_lds(
        (const __attribute__((address_space(1))) void*)g,
        (__attribute__((address_space(3))) void*)l,
        16, 0, 0);
}

// ---- DPP row_ror reduces over 16-lane groups ----
template<int CTRL>
static __device__ __forceinline__ float dppf(float v) {
    return __builtin_bit_cast(float,
        __builtin_amdgcn_update_dpp(0, __builtin_bit_cast(int, v), CTRL, 0xF, 0xF, false));
}
template<int CTRL>
static __device__ __forceinline__ int dppi(int v) {
    return __builtin_amdgcn_update_dpp(0, v, CTRL, 0xF, 0xF, false);
}
static __device__ __forceinline__ float sum16f(float v) {
    v += dppf<0x121>(v); v += dppf<0x122>(v); v += dppf<0x124>(v); v += dppf<0x128>(v);
    return v;
}
static __device__ __forceinline__ float max16f(float v) {
    v = fmaxf(v, dppf<0x121>(v)); v = fmaxf(v, dppf<0x122>(v));
    v = fmaxf(v, dppf<0x124>(v)); v = fmaxf(v, dppf<0x128>(v));
    return v;
}
static __device__ __forceinline__ unsigned sum16u(unsigned v) {
    v += (unsigned)dppi<0x121>((int)v); v += (unsigned)dppi<0x122>((int)v);
    v += (unsigned)dppi<0x124>((int)v); v += (unsigned)dppi<0x128>((int)v);
    return v;
}

// raw barrier helpers (no vmcnt drain)
static __device__ __forceinline__ void bar_only() {
    __builtin_amdgcn_sched_barrier(0);
    __builtin_amdgcn_s_barrier();
    __builtin_amdgcn_sched_barrier(0);
}
static __device__ __forceinline__ void bar_lgkm() {
    asm volatile("s_waitcnt lgkmcnt(0)" ::: "memory");
    __builtin_amdgcn_sched_barrier(0);
    __builtin_amdgcn_s_barrier();
    __builtin_amdgcn_sched_barrier(0);
}

// ---------------- prep: W1 (E x H) -> W1T bf16 (H x E); W2 (H x M) -> W2T bf16 (M x H)
__global__ void prep_weights(const float* __restrict__ W1, const float* __restrict__ W2,
                             unsigned short* __restrict__ W1T, unsigned short* __restrict__ W2T)
{
    const int b = blockIdx.x, tid = threadIdx.x;
    if (b < 64) {
        const int e0 = b * 8, h = tid;
        short8 sv;
#pragma unroll
        for (int j = 0; j < 8; ++j)
            sv[j] = (short)f2bf(W1[(size_t)(e0 + j) * HH + h]);
        *(short8*)(void*)(W1T + (size_t)h * EE + e0) = sv;
    } else {
        const int h0 = (b - 64) * 16;
        if (tid < MM) {
            const int m = tid;
            short8 s0v, s1v;
#pragma unroll
            for (int j = 0; j < 8; ++j) {
                s0v[j] = (short)f2bf(W2[(size_t)(h0 + j) * MM + m]);
                s1v[j] = (short)f2bf(W2[(size_t)(h0 + 8 + j) * MM + m]);
            }
            *(short8*)(void*)(W2T + (size_t)m * HH + h0) = s0v;
            *(short8*)(void*)(W2T + (size_t)m * HH + h0 + 8) = s1v;
        }
    }
}

// ---------------- fused main: 128 rows/block, 512 threads (8 waves, 2Mrow x 4Ncol)
// LDS 64 KB: 4x 16KB x-chunk buffers (f32, K=32 each, source-permuted) ->
//            h bf16 [128][256] swizzled -> logits f32 [128][128] swizzled.
// K-loop: counted vmcnt(4), depth-3 prefetch, ONE raw barrier per chunk (T3/T4).
__global__ __launch_bounds__(512, 4)
void gene_router_kernel(const float* __restrict__ x,
                        const int*   __restrict__ mask,
                        const float* __restrict__ noise,
                        const unsigned short* __restrict__ W1T,
                        const float* __restrict__ b1,
                        const unsigned short* __restrict__ W2T,
                        const float* __restrict__ b2,
                        float* __restrict__ out,
                        float* __restrict__ outk)
{
    __shared__ __align__(16) unsigned char lds[65536];

    const int tid = threadIdx.x;
    const int c   = blockIdx.y;
    const int s0  = blockIdx.x * 128;

    const int w    = tid >> 6;      // wave 0..7
    const int lane = tid & 63;
    const int lr   = lane & 15;
    const int kq   = lane >> 4;
    const int wr   = w >> 2;        // 0..1 (row half)
    const int wc   = w & 3;         // 0..3 (col quarter)
    const int tx   = tid & 15;
    const int ty   = tid >> 4;      // 0..31

    // ---- outk early ----
    if (tid < 128) {
        const int s = s0 + tid;
        if (s < SS)
            outk[(size_t)c * SS + s] = (mask[(size_t)c * LL + s + 1] != 0) ? 1.0f : 0.0f;
    }

    const float* xb = x + ((size_t)c * LL + s0 + 1) * EE;

    // stage chunk ck (K=32 f32 = 1024x16B units) into buffer (ck&3).
    // unit u -> row=u>>3, uu=u&7; LDS holds source col-unit (uu^(row&7)). Linear dest.
#define STAGE(ck) do {                                                      \
    const int bo_ = ((ck) & 3) * 16384;                                     \
    _Pragma("unroll")                                                       \
    for (int j_ = 0; j_ < 2; ++j_) {                                        \
        const int unit_ = j_ * 512 + tid;                                   \
        const int row_ = unit_ >> 3, uu_ = unit_ & 7;                       \
        const int rs_  = min(s0 + row_, SS - 1) - s0;                       \
        const float* g_ = xb + (size_t)rs_ * EE + (ck) * 32                 \
                          + ((uu_ ^ (row_ & 7)) << 2);                      \
        gl2lds16(g_, lds + bo_ + unit_ * 16);                               \
    } } while (0)

    const int cw = wc * 64;
    float b1v[4];
#pragma unroll
    for (int n = 0; n < 4; ++n) b1v[n] = b1[cw + n * 16 + lr];

    // ---- GEMM1: h[128][256] = relu(xs @ W1 + b1), 16 chunks, counted-vmcnt pipe ----
    f32x4 acc[4][4];
#pragma unroll
    for (int r = 0; r < 4; ++r)
#pragma unroll
        for (int n = 0; n < 4; ++n) acc[r][n] = (f32x4)0.0f;

    STAGE(0); STAGE(1); STAGE(2);

    // per chunk: wait own chunk's loads (vmcnt W, never drain) -> barrier ->
    // stage(c+3) into buf (c-1)&3 (proven consumed by the barrier) -> compute.
#define DO_CHUNK(C, W) do {                                                 \
    asm volatile("s_waitcnt vmcnt(" #W ")" ::: "memory");                   \
    __builtin_amdgcn_sched_barrier(0);                                      \
    __builtin_amdgcn_s_barrier();                                           \
    __builtin_amdgcn_sched_barrier(0);                                      \
    if ((C) < 13) STAGE((C) + 3);                                           \
    const unsigned char* cb_ = lds + ((C) & 3) * 16384;                     \
    short8 af_[4];                                                          \
    _Pragma("unroll")                                                       \
    for (int r_ = 0; r_ < 4; ++r_) {                                        \
        const int row_ = wr * 64 + r_ * 16 + lr;                            \
        const float4 a0_ = *(const float4*)(const void*)                    \
            (cb_ + row_ * 128 + (((kq * 2 + 0) ^ (row_ & 7)) << 4));        \
        const float4 a1_ = *(const float4*)(const void*)                    \
            (cb_ + row_ * 128 + (((kq * 2 + 1) ^ (row_ & 7)) << 4));        \
        af_[r_] = cvt8(a0_, a1_);                                           \
    }                                                                       \
    short8 bw_[4];                                                          \
    _Pragma("unroll")                                                       \
    for (int n_ = 0; n_ < 4; ++n_)                                          \
        bw_[n_] = *(const short8*)(const void*)                             \
            (W1T + (size_t)(cw + n_ * 16 + lr) * EE + (C) * 32 + kq * 8);   \
    _Pragma("unroll")                                                       \
    for (int r_ = 0; r_ < 4; ++r_)                                          \
        _Pragma("unroll")                                                   \
        for (int n_ = 0; n_ < 4; ++n_)                                      \
            acc[r_][n_] = __builtin_amdgcn_mfma_f32_16x16x32_bf16(          \
                af_[r_], bw_[n_], acc[r_][n_], 0, 0, 0);                    \
    } while (0)

    DO_CHUNK( 0, 4); DO_CHUNK( 1, 4); DO_CHUNK( 2, 4); DO_CHUNK( 3, 4);
    DO_CHUNK( 4, 4); DO_CHUNK( 5, 4); DO_CHUNK( 6, 4); DO_CHUNK( 7, 4);
    DO_CHUNK( 8, 4); DO_CHUNK( 9, 4); DO_CHUNK(10, 4); DO_CHUNK(11, 4);
    DO_CHUNK(12, 4); DO_CHUNK(13, 4); DO_CHUNK(14, 2); DO_CHUNK(15, 0);

    bar_only();   // all chunk-15 reads done before h overlays the buffers

    // ---- bias + relu -> h bf16 [128][256] swizzled (overlays staging) ----
#pragma unroll
    for (int n = 0; n < 4; ++n) {
        const int colh = cw + n * 16 + lr;
#pragma unroll
        for (int r = 0; r < 4; ++r)
#pragma unroll
            for (int q = 0; q < 4; ++q) {
                const int row = wr * 64 + r * 16 + kq * 4 + q;
                *(unsigned short*)(lds + row * 512 + ((colh * 2) ^ ((row & 7) << 4))) =
                    f2bf(fmaxf(acc[r][n][q] + b1v[n], 0.0f));
            }
    }
    bar_lgkm();   // h visible

    // ---- prefetch epilogue inputs (stay in flight through GEMM2: no vmcnt drains) ----
    float4 nz[4][2];
    int mk[4];
#pragma unroll
    for (int i = 0; i < 4; ++i) {
        const int s  = s0 + ty * 4 + i;
        const int sc = min(s, SS - 1);
        const float* np_ = noise + ((size_t)c * SS + sc) * MM + tx * 8;
        nz[i][0] = *(const float4*)np_;
        nz[i][1] = *(const float4*)(np_ + 4);
        mk[i] = mask[(size_t)c * LL + sc + 1];
    }
    const float4 b2a = *(const float4*)(b2 + tx * 8);
    const float4 b2b = *(const float4*)(b2 + tx * 8 + 4);

    // ---- GEMM2: logits[128][128] = h @ W2 ----
    f32x4 acc2[4][2];
#pragma unroll
    for (int r = 0; r < 4; ++r)
#pragma unroll
        for (int n = 0; n < 2; ++n) acc2[r][n] = (f32x4)0.0f;

    const int cw2 = wc * 32;
#pragma unroll 4
    for (int ks = 0; ks < 8; ++ks) {
        short8 ah[4];
#pragma unroll
        for (int r = 0; r < 4; ++r) {
            const int row = wr * 64 + r * 16 + lr;
            ah[r] = *(const short8*)(const void*)
                (lds + row * 512 + ((ks * 64 + kq * 16) ^ ((row & 7) << 4)));
        }
        short8 bw[2];
#pragma unroll
        for (int n = 0; n < 2; ++n)
            bw[n] = *(const short8*)(const void*)
                (W2T + (size_t)(cw2 + n * 16 + lr) * HH + ks * 32 + kq * 8);
#pragma unroll
        for (int r = 0; r < 4; ++r)
#pragma unroll
            for (int n = 0; n < 2; ++n)
                acc2[r][n] = __builtin_amdgcn_mfma_f32_16x16x32_bf16(ah[r], bw[n], acc2[r][n], 0, 0, 0);
    }
    bar_lgkm();   // all h reads done; overlay logits

    // ---- logits f32 [128][128] swizzled into same region ----
#pragma unroll
    for (int r = 0; r < 4; ++r)
#pragma unroll
        for (int n = 0; n < 2; ++n)
#pragma unroll
            for (int q = 0; q < 4; ++q) {
                const int row = wr * 64 + r * 16 + kq * 4 + q;
                const int col = cw2 + n * 16 + lr;
                *(float*)(lds + row * 512
                          + ((((col >> 2) << 4) ^ ((row & 7) << 4)) | ((col & 3) << 2)))
                    = acc2[r][n][q];
            }
    bar_lgkm();

    // ---- epilogue: 4 rows/thread ----
    float b2v[8] = {b2a.x, b2a.y, b2a.z, b2a.w, b2b.x, b2b.y, b2b.z, b2b.w};

    float pr[4][8];
    float pmaxv[4];
#pragma unroll
    for (int i = 0; i < 4; ++i) {
        const int row = ty * 4 + i;
        const float4 l0 = *(const float4*)(const void*)
            (lds + row * 512 + ((tx * 32) ^ ((row & 7) << 4)));
        const float4 l1 = *(const float4*)(const void*)
            (lds + row * 512 + ((tx * 32 + 16) ^ ((row & 7) << 4)));
        const float lg[8] = {l0.x, l0.y, l0.z, l0.w, l1.x, l1.y, l1.z, l1.w};
        const float uu[8] = {nz[i][0].x, nz[i][0].y, nz[i][0].z, nz[i][0].w,
                             nz[i][1].x, nz[i][1].y, nz[i][1].z, nz[i][1].w};
        float pm[8];
#pragma unroll
        for (int q = 0; q < 8; ++q) {
            const float g = -__logf(-__logf(uu[q] + 1e-20f) + 1e-20f);
            pm[q] = lg[q] + b2v[q] + g;
        }
        float mx = pm[0];
#pragma unroll
        for (int q = 1; q < 8; ++q) mx = fmaxf(mx, pm[q]);
        mx = max16f(mx);
        float se = 0.0f;
#pragma unroll
        for (int q = 0; q < 8; ++q) { pr[i][q] = __expf(pm[q] - mx); se += pr[i][q]; }
        se = sum16f(se);
        const float inv = 1.0f / se;
#pragma unroll
        for (int q = 0; q < 8; ++q) pr[i][q] *= inv;
        pmaxv[i] = inv;   // max prob == exp(0)*inv
    }

    // ---- top-K threshold: 4-row packed bisection, 16 iters ----
    float lo[4], hi[4];
#pragma unroll
    for (int i = 0; i < 4; ++i) { lo[i] = 0.0f; hi[i] = fminf(pmaxv[i], 1.0f / 30.0f); }
    for (int it = 0; it < 16; ++it) {
        float mid[4];
#pragma unroll
        for (int i = 0; i < 4; ++i) mid[i] = 0.5f * (lo[i] + hi[i]);
        unsigned cnt = 0;
#pragma unroll
        for (int q = 0; q < 8; ++q) {
            cnt += (pr[0][q] > mid[0]) ? 1u : 0u;
            cnt += (pr[1][q] > mid[1]) ? (1u << 8) : 0u;
            cnt += (pr[2][q] > mid[2]) ? (1u << 16) : 0u;
            cnt += (pr[3][q] > mid[3]) ? (1u << 24) : 0u;
        }
        cnt = sum16u(cnt);
#pragma unroll
        for (int i = 0; i < 4; ++i) {
            const bool ge = ((cnt >> (8 * i)) & 255u) >= TOPK;
            lo[i] = ge ? mid[i] : lo[i];
            hi[i] = ge ? hi[i] : mid[i];
        }
    }

    // ---- sigmoid gate + mask + store ----
#pragma unroll
    for (int i = 0; i < 4; ++i) {
        const int s = s0 + ty * 4 + i;
        if (s < SS) {
            const float mz = (mk[i] != 0) ? 0.0f : 1.0f;
            float ov[8];
#pragma unroll
            for (int q = 0; q < 8; ++q) {
                const float sm = 1.0f / (1.0f + __expf((hi[i] - pr[i][q]) * 100.0f));
                ov[q] = pr[i][q] * sm * mz;
            }
            float* op = out + ((size_t)c * SS + s) * MM + tx * 8;
            float4 o0, o1;
            o0.x=ov[0]; o0.y=ov[1]; o0.z=ov[2]; o0.w=ov[3];
            o1.x=ov[4]; o1.y=ov[5]; o1.z=ov[6]; o1.w=ov[7];
            *(float4*)(op + 0) = o0;
            *(float4*)(op + 4) = o1;
        }
    }
#undef DO_CHUNK
#undef STAGE
}

extern "C" void kernel_launch(void* const* d_in, const int* in_sizes, int n_in,
                              void* d_out, int out_size, void* d_ws, size_t ws_size,
                              hipStream_t stream) {
    const float* x     = (const float*)d_in[0];
    const int*   mask  = (const int*)d_in[1];
    const float* noise = (const float*)d_in[2];
    const float* W1    = (const float*)d_in[3];
    const float* b1    = (const float*)d_in[4];
    const float* W2    = (const float*)d_in[5];
    const float* b2    = (const float*)d_in[6];
    float* out  = (float*)d_out;
    float* outk = out + (size_t)CC * SS * MM;

    unsigned short* W1T = (unsigned short*)d_ws;            // 256 x 512 bf16 = 256 KB
    unsigned short* W2T = W1T + (size_t)HH * EE;            // 128 x 256 bf16 =  64 KB

    prep_weights<<<dim3(80), dim3(256), 0, stream>>>(W1, W2, W1T, W2T);

    dim3 grid(64, CC);   // 64 blocks x 128 rows = 8192 >= 8191
    gene_router_kernel<<<grid, dim3(512), 0, stream>>>(x, mask, noise, W1T, b1, W2T, b2, out, outk);
}

// Round 9
// 177.062 us; speedup vs baseline: 1.0513x; 1.0513x over previous
//
#include <hip/hip_runtime.h>
#include <hip/hip_bf16.h>

#define CC 16
#define LL 8192
#define SS 8191   // L-1
#define EE 512
#define HH 256
#define MM 128
#define TOPK 30
#define TOT (CC * SS)   // 131056 rows

typedef __attribute__((ext_vector_type(8))) short short8;
typedef __attribute__((ext_vector_type(4))) float f32x4;
typedef __attribute__((ext_vector_type(4))) unsigned int u32x4;

static __device__ __forceinline__ unsigned short f2bf(float f) {
    unsigned u = __builtin_bit_cast(unsigned, f);
    u += 0x7FFFu + ((u >> 16) & 1u);   // RNE
    return (unsigned short)(u >> 16);
}

static __device__ __forceinline__ unsigned pk2(float lo, float hi) {
    __hip_bfloat162 t = __float22bfloat162_rn(float2{lo, hi});
    unsigned u;
    __builtin_memcpy(&u, &t, 4);
    return u;
}

// 8 f32 -> 8 bf16 (v_cvt_pk_bf16_f32)
static __device__ __forceinline__ short8 cvt8(const float4 a, const float4 b) {
    u32x4 uv;
    uv[0] = pk2(a.x, a.y);
    uv[1] = pk2(a.z, a.w);
    uv[2] = pk2(b.x, b.y);
    uv[3] = pk2(b.z, b.w);
    return __builtin_bit_cast(short8, uv);
}

// async global->LDS, 16B per lane
static __device__ __forceinline__ void gl2lds16(const float* g, unsigned char* l) {
    __builtin_amdgcn_global_load_lds(
        (const __attribute__((address_space(1))) void*)g,
        (__attribute__((address_space(3))) void*)l,
        16, 0, 0);
}

// ---- DPP row_ror reduces over 16-lane groups ----
template<int CTRL>
static __device__ __forceinline__ float dppf(float v) {
    return __builtin_bit_cast(float,
        __builtin_amdgcn_update_dpp(0, __builtin_bit_cast(int, v), CTRL, 0xF, 0xF, false));
}
template<int CTRL>
static __device__ __forceinline__ int dppi(int v) {
    return __builtin_amdgcn_update_dpp(0, v, CTRL, 0xF, 0xF, false);
}
static __device__ __forceinline__ float sum16f(float v) {
    v += dppf<0x121>(v); v += dppf<0x122>(v); v += dppf<0x124>(v); v += dppf<0x128>(v);
    return v;
}
static __device__ __forceinline__ float max16f(float v) {
    v = fmaxf(v, dppf<0x121>(v)); v = fmaxf(v, dppf<0x122>(v));
    v = fmaxf(v, dppf<0x124>(v)); v = fmaxf(v, dppf<0x128>(v));
    return v;
}
static __device__ __forceinline__ unsigned sum16u(unsigned v) {
    v += (unsigned)dppi<0x121>((int)v); v += (unsigned)dppi<0x122>((int)v);
    v += (unsigned)dppi<0x124>((int)v); v += (unsigned)dppi<0x128>((int)v);
    return v;
}

// ---------------- prep: W1 (E x H) -> W1T bf16 (H x E); W2 (H x M) -> W2T bf16 (M x H)
__global__ void prep_weights(const float* __restrict__ W1, const float* __restrict__ W2,
                             unsigned short* __restrict__ W1T, unsigned short* __restrict__ W2T)
{
    const int b = blockIdx.x, tid = threadIdx.x;
    if (b < 64) {
        const int e0 = b * 8, h = tid;
        short8 sv;
#pragma unroll
        for (int j = 0; j < 8; ++j)
            sv[j] = (short)f2bf(W1[(size_t)(e0 + j) * HH + h]);
        *(short8*)(void*)(W1T + (size_t)h * EE + e0) = sv;
    } else {
        const int h0 = (b - 64) * 16;
        if (tid < MM) {
            const int m = tid;
            short8 s0v, s1v;
#pragma unroll
            for (int j = 0; j < 8; ++j) {
                s0v[j] = (short)f2bf(W2[(size_t)(h0 + j) * MM + m]);
                s1v[j] = (short)f2bf(W2[(size_t)(h0 + 8 + j) * MM + m]);
            }
            *(short8*)(void*)(W2T + (size_t)m * HH + h0) = s0v;
            *(short8*)(void*)(W2T + (size_t)m * HH + h0 + 8) = s1v;
        }
    }
}

// ---------------- K1: GEMM-only. 128 rows/block, 512 threads (8 waves, 2Mrow x 4Ncol).
// logits f32 written directly to the out region (K2 overwrites in place).
__global__ __launch_bounds__(512, 4)
void gene_gemm_kernel(const float* __restrict__ x,
                      const unsigned short* __restrict__ W1T,
                      const float* __restrict__ b1,
                      const unsigned short* __restrict__ W2T,
                      float* __restrict__ logits)
{
    __shared__ __align__(16) unsigned char lds[65536];

    const int tid = threadIdx.x;
    const int c   = blockIdx.y;
    const int s0  = blockIdx.x * 128;

    const int w    = tid >> 6;
    const int lane = tid & 63;
    const int lr   = lane & 15;
    const int kq   = lane >> 4;
    const int wr   = w >> 2;
    const int wc   = w & 3;
    const int tx   = tid & 15;
    const int ty   = tid >> 4;

    const float* xb = x + ((size_t)c * LL + s0 + 1) * EE;

    // stage chunk ck (K=64 f32) into buffer (ck&1); source XOR-permuted, dest linear.
#define STAGE(ck, bufoff) do {                                              \
    _Pragma("unroll")                                                       \
    for (int it_ = 0; it_ < 4; ++it_) {                                     \
        const int row_ = it_ * 32 + ty;                                     \
        const int rs_  = min(s0 + row_, SS - 1) - s0;                       \
        const float* g_ = xb + (size_t)rs_ * EE + (ck) * 64                 \
                          + ((tx ^ (row_ & 7)) << 2);                       \
        gl2lds16(g_, lds + (bufoff) + (it_ * 512 + tid) * 16);              \
    } } while (0)

    const int cw = wc * 64;
    float b1v[4];
#pragma unroll
    for (int n = 0; n < 4; ++n) b1v[n] = b1[cw + n * 16 + lr];

    // ---- GEMM1: h[128][256] = relu(xs @ W1 + b1), K chunked 8x64, dbuf ----
    f32x4 acc[4][4];
#pragma unroll
    for (int r = 0; r < 4; ++r)
#pragma unroll
        for (int n = 0; n < 4; ++n) acc[r][n] = (f32x4)0.0f;

    STAGE(0, 0);
    __syncthreads();

    for (int ck = 0; ck < 8; ++ck) {
        const int cur = (ck & 1) << 15;
        if (ck < 7) STAGE(ck + 1, ((ck + 1) & 1) << 15);
#pragma unroll
        for (int ks = 0; ks < 2; ++ks) {
            short8 af[4];
#pragma unroll
            for (int r = 0; r < 4; ++r) {
                const int row = wr * 64 + r * 16 + lr;
                const int ug  = ks * 8 + kq * 2;
                const float4 a0 = *(const float4*)(const void*)
                    (lds + cur + row * 256 + (((ug + 0) ^ (row & 7)) << 4));
                const float4 a1 = *(const float4*)(const void*)
                    (lds + cur + row * 256 + (((ug + 1) ^ (row & 7)) << 4));
                af[r] = cvt8(a0, a1);
            }
            short8 bf_[4];
#pragma unroll
            for (int n = 0; n < 4; ++n)
                bf_[n] = *(const short8*)(const void*)
                    (W1T + (size_t)(cw + n * 16 + lr) * EE + ck * 64 + ks * 32 + kq * 8);
#pragma unroll
            for (int r = 0; r < 4; ++r)
#pragma unroll
                for (int n = 0; n < 4; ++n)
                    acc[r][n] = __builtin_amdgcn_mfma_f32_16x16x32_bf16(af[r], bf_[n], acc[r][n], 0, 0, 0);
        }
        __syncthreads();
    }

    // ---- bias + relu -> h bf16 [128][256] swizzled (overlays staging) ----
#pragma unroll
    for (int n = 0; n < 4; ++n) {
        const int colh = cw + n * 16 + lr;
#pragma unroll
        for (int r = 0; r < 4; ++r)
#pragma unroll
            for (int q = 0; q < 4; ++q) {
                const int row = wr * 64 + r * 16 + kq * 4 + q;
                *(unsigned short*)(lds + row * 512 + ((colh * 2) ^ ((row & 7) << 4))) =
                    f2bf(fmaxf(acc[r][n][q] + b1v[n], 0.0f));
            }
    }
    __syncthreads();

    // ---- GEMM2: logits[128][128] = h @ W2 ----
    f32x4 acc2[4][2];
#pragma unroll
    for (int r = 0; r < 4; ++r)
#pragma unroll
        for (int n = 0; n < 2; ++n) acc2[r][n] = (f32x4)0.0f;

    const int cw2 = wc * 32;
#pragma unroll 4
    for (int ks = 0; ks < 8; ++ks) {
        short8 ah[4];
#pragma unroll
        for (int r = 0; r < 4; ++r) {
            const int row = wr * 64 + r * 16 + lr;
            ah[r] = *(const short8*)(const void*)
                (lds + row * 512 + ((ks * 64 + kq * 16) ^ ((row & 7) << 4)));
        }
        short8 bw[2];
#pragma unroll
        for (int n = 0; n < 2; ++n)
            bw[n] = *(const short8*)(const void*)
                (W2T + (size_t)(cw2 + n * 16 + lr) * HH + ks * 32 + kq * 8);
#pragma unroll
        for (int r = 0; r < 4; ++r)
#pragma unroll
            for (int n = 0; n < 2; ++n)
                acc2[r][n] = __builtin_amdgcn_mfma_f32_16x16x32_bf16(ah[r], bw[n], acc2[r][n], 0, 0, 0);
    }

    // ---- direct global store of logits ----
#pragma unroll
    for (int r = 0; r < 4; ++r)
#pragma unroll
        for (int n = 0; n < 2; ++n)
#pragma unroll
            for (int q = 0; q < 4; ++q) {
                const int s = s0 + wr * 64 + r * 16 + kq * 4 + q;
                if (s < SS)
                    logits[((size_t)c * SS + s) * MM + cw2 + n * 16 + lr] = acc2[r][n][q];
            }
#undef STAGE
}

// ---------------- K2: epilogue-only. Barrier-free, LDS-free. 64 rows/block, 256 thr.
// Reads logits from out (written by K1), rewrites out in place with gated probs.
__global__ __launch_bounds__(256, 8)
void gene_epi_kernel(const float* __restrict__ noise,
                     const int*   __restrict__ mask,
                     const float* __restrict__ b2,
                     float* __restrict__ out,
                     float* __restrict__ outk)
{
    const int tid = threadIdx.x;
    const int tx  = tid & 15;
    const int ty  = tid >> 4;
    const long base = (long)blockIdx.x * 64;

    // outk (coalesced, one per row)
    if (tid < 64) {
        const long gr = base + tid;
        if (gr < TOT) {
            const int cc2 = (int)(gr / SS);
            outk[gr] = (mask[gr + cc2 + 1] != 0) ? 1.0f : 0.0f;
        }
    }

    float b2v[8];
    {
        const float4 bb0 = *(const float4*)(b2 + tx * 8 + 0);
        const float4 bb1 = *(const float4*)(b2 + tx * 8 + 4);
        b2v[0]=bb0.x; b2v[1]=bb0.y; b2v[2]=bb0.z; b2v[3]=bb0.w;
        b2v[4]=bb1.x; b2v[5]=bb1.y; b2v[6]=bb1.z; b2v[7]=bb1.w;
    }

    float pr[4][8];
    float pmaxv[4];
    float mz[4];
    long  grv[4];

#pragma unroll
    for (int i = 0; i < 4; ++i) {
        const long gr  = base + ty * 4 + i;
        grv[i] = gr;
        const long grc = gr < TOT ? gr : (TOT - 1);
        const int  cc2 = (int)(grc / SS);
        mz[i] = (mask[grc + cc2 + 1] != 0) ? 0.0f : 1.0f;

        const float* lp = out   + grc * MM + tx * 8;
        const float* np = noise + grc * MM + tx * 8;
        const float4 l0 = *(const float4*)lp;
        const float4 l1 = *(const float4*)(lp + 4);
        const float4 u0 = *(const float4*)np;
        const float4 u1 = *(const float4*)(np + 4);
        const float lg[8] = {l0.x,l0.y,l0.z,l0.w,l1.x,l1.y,l1.z,l1.w};
        const float uu[8] = {u0.x,u0.y,u0.z,u0.w,u1.x,u1.y,u1.z,u1.w};
        float pm[8];
#pragma unroll
        for (int q = 0; q < 8; ++q) {
            const float g = -__logf(-__logf(uu[q] + 1e-20f) + 1e-20f);
            pm[q] = lg[q] + b2v[q] + g;
        }
        float mx = pm[0];
#pragma unroll
        for (int q = 1; q < 8; ++q) mx = fmaxf(mx, pm[q]);
        mx = max16f(mx);
        float se = 0.0f;
#pragma unroll
        for (int q = 0; q < 8; ++q) { pr[i][q] = __expf(pm[q] - mx); se += pr[i][q]; }
        se = sum16f(se);
        const float inv = 1.0f / se;
#pragma unroll
        for (int q = 0; q < 8; ++q) pr[i][q] *= inv;
        pmaxv[i] = inv;   // max prob == exp(0)*inv
    }

    // ---- top-K threshold: 4-row packed bisection, 10 iters (width ~3e-5) ----
    float lo[4], hi[4];
#pragma unroll
    for (int i = 0; i < 4; ++i) { lo[i] = 0.0f; hi[i] = fminf(pmaxv[i], 1.0f / 30.0f); }
    for (int it = 0; it < 10; ++it) {
        float mid[4];
#pragma unroll
        for (int i = 0; i < 4; ++i) mid[i] = 0.5f * (lo[i] + hi[i]);
        unsigned cnt = 0;
#pragma unroll
        for (int q = 0; q < 8; ++q) {
            cnt += (pr[0][q] > mid[0]) ? 1u : 0u;
            cnt += (pr[1][q] > mid[1]) ? (1u << 8) : 0u;
            cnt += (pr[2][q] > mid[2]) ? (1u << 16) : 0u;
            cnt += (pr[3][q] > mid[3]) ? (1u << 24) : 0u;
        }
        cnt = sum16u(cnt);
#pragma unroll
        for (int i = 0; i < 4; ++i) {
            const bool ge = ((cnt >> (8 * i)) & 255u) >= TOPK;
            lo[i] = ge ? mid[i] : lo[i];
            hi[i] = ge ? hi[i] : mid[i];
        }
    }

    // ---- sigmoid gate + mask + store (in place) ----
#pragma unroll
    for (int i = 0; i < 4; ++i) {
        if (grv[i] < TOT) {
            float ov[8];
#pragma unroll
            for (int q = 0; q < 8; ++q) {
                const float sm = 1.0f / (1.0f + __expf((hi[i] - pr[i][q]) * 100.0f));
                ov[q] = pr[i][q] * sm * mz[i];
            }
            float* op = out + grv[i] * MM + tx * 8;
            float4 o0, o1;
            o0.x=ov[0]; o0.y=ov[1]; o0.z=ov[2]; o0.w=ov[3];
            o1.x=ov[4]; o1.y=ov[5]; o1.z=ov[6]; o1.w=ov[7];
            *(float4*)(op + 0) = o0;
            *(float4*)(op + 4) = o1;
        }
    }
}

extern "C" void kernel_launch(void* const* d_in, const int* in_sizes, int n_in,
                              void* d_out, int out_size, void* d_ws, size_t ws_size,
                              hipStream_t stream) {
    const float* x     = (const float*)d_in[0];
    const int*   mask  = (const int*)d_in[1];
    const float* noise = (const float*)d_in[2];
    const float* W1    = (const float*)d_in[3];
    const float* b1    = (const float*)d_in[4];
    const float* W2    = (const float*)d_in[5];
    const float* b2    = (const float*)d_in[6];
    float* out  = (float*)d_out;
    float* outk = out + (size_t)CC * SS * MM;

    unsigned short* W1T = (unsigned short*)d_ws;            // 256 x 512 bf16 = 256 KB
    unsigned short* W2T = W1T + (size_t)HH * EE;            // 128 x 256 bf16 =  64 KB

    prep_weights<<<dim3(80), dim3(256), 0, stream>>>(W1, W2, W1T, W2T);

    // K1: logits -> out region
    gene_gemm_kernel<<<dim3(64, CC), dim3(512), 0, stream>>>(x, W1T, b1, W2T, out);

    // K2: epilogue in place
    const int nblk = (TOT + 63) / 64;   // 2048
    gene_epi_kernel<<<dim3(nblk), dim3(256), 0, stream>>>(noise, mask, b2, out, outk);
}